// Round 1
// 901.364 us; speedup vs baseline: 1.0326x; 1.0326x over previous
//
#include <hip/hip_runtime.h>
#include <hip/hip_bf16.h>
#include <math.h>

typedef __bf16 bf16;
typedef __bf16 bf16x8 __attribute__((ext_vector_type(8)));
typedef float f32x4 __attribute__((ext_vector_type(4)));

#define MFMA(a, b, c) __builtin_amdgcn_mfma_f32_16x16x32_bf16((a), (b), (c), 0, 0, 0)

// async global->LDS, 16B per lane. LDS dest must be wave-uniform base + lane*16.
static __device__ __forceinline__ void gl16(const bf16* g, bf16* l) {
  __builtin_amdgcn_global_load_lds(
      (const __attribute__((address_space(1))) void*)g,
      (__attribute__((address_space(3))) void*)l, 16, 0, 0);
}

static __device__ __forceinline__ bf16x8 bzero8() {
  bf16x8 v;
#pragma unroll
  for (int i = 0; i < 8; ++i) v[i] = (bf16)0.0f;
  return v;
}

// ---------- W (K x N fp32, row-major) -> Wt (N x K bf16, row-major) ----------
__global__ void k_transpose_cvt(const float* __restrict__ W, bf16* __restrict__ Wt,
                                int K, int N) {
  __shared__ float tile[32][33];
  int k0 = blockIdx.x * 32, n0 = blockIdx.y * 32;
  int tx = threadIdx.x & 31, ty = threadIdx.x >> 5;
  for (int i = ty; i < 32; i += 8)
    tile[i][tx] = W[(size_t)(k0 + i) * N + (n0 + tx)];
  __syncthreads();
  for (int i = ty; i < 32; i += 8)
    Wt[(size_t)(n0 + i) * K + (k0 + tx)] = (bf16)tile[tx][i];
}

// ---------- V (rows x 1024 bf16, token-major) -> Vt[b][h][d][kvpad] ----------
__global__ void k_transpose_v(const bf16* __restrict__ V, bf16* __restrict__ Vt,
                              int rows, int kvpad) {
  __shared__ __attribute__((aligned(16))) bf16 tile[64][72];
  int t0 = blockIdx.x * 64, h = blockIdx.y, b = blockIdx.z;
  int t = threadIdx.x;
  int tr = t >> 2, c0 = (t & 3) * 16;
  int token = t0 + tr;
  bf16x8 a = bzero8(), bv = bzero8();
  if (token < rows) {
    const bf16* src = V + ((size_t)(b * rows + token)) * 1024 + h * 64 + c0;
    a = *(const bf16x8*)src;
    bv = *(const bf16x8*)(src + 8);
  }
  *(bf16x8*)&tile[tr][c0] = a;
  *(bf16x8*)&tile[tr][c0 + 8] = bv;
  __syncthreads();
  int d = t >> 2, tq = (t & 3) * 16;
  bf16x8 o1, o2;
#pragma unroll
  for (int i = 0; i < 8; ++i) { o1[i] = tile[tq + i][d]; o2[i] = tile[tq + 8 + i][d]; }
  bf16* dst = Vt + ((size_t)((b * 16 + h) * 64 + d)) * kvpad + t0 + tq;
  *(bf16x8*)dst = o1;
  *(bf16x8*)(dst + 8) = o2;
}

// ---------- fp32 -> bf16 flat convert ----------
__global__ void k_cvt(const float* __restrict__ in, bf16* __restrict__ out, int n) {
  int i = blockIdx.x * 256 + threadIdx.x;
  if (i < n) out[i] = (bf16)in[i];
}

// ---------- LayerNorm over D=1024, one block per row, bf16 out ----------
__global__ void k_layernorm(const float* __restrict__ x, const float* __restrict__ g,
                            const float* __restrict__ b, bf16* __restrict__ out) {
  int row = blockIdx.x;
  float4 v = ((const float4*)(x + (size_t)row * 1024))[threadIdx.x];
  float s = v.x + v.y + v.z + v.w;
  float ss = v.x * v.x + v.y * v.y + v.z * v.z + v.w * v.w;
#pragma unroll
  for (int off = 1; off < 64; off <<= 1) {
    s += __shfl_xor(s, off);
    ss += __shfl_xor(ss, off);
  }
  __shared__ float sm[4], sm2[4];
  int w = threadIdx.x >> 6;
  if ((threadIdx.x & 63) == 0) { sm[w] = s; sm2[w] = ss; }
  __syncthreads();
  s = sm[0] + sm[1] + sm[2] + sm[3];
  ss = sm2[0] + sm2[1] + sm2[2] + sm2[3];
  float mu = s * (1.0f / 1024.0f);
  float var = ss * (1.0f / 1024.0f) - mu * mu;
  float rs = rsqrtf(var + 1e-5f);
  float4 gg = ((const float4*)g)[threadIdx.x];
  float4 bb = ((const float4*)b)[threadIdx.x];
  bf16* o = out + (size_t)row * 1024 + threadIdx.x * 4;
  o[0] = (bf16)((v.x - mu) * rs * gg.x + bb.x);
  o[1] = (bf16)((v.y - mu) * rs * gg.y + bb.y);
  o[2] = (bf16)((v.z - mu) * rs * gg.z + bb.z);
  o[3] = (bf16)((v.w - mu) * rs * gg.w + bb.w);
}

// ---------- GEMM: C[M,N] = A[M,K] @ Bt[N,K]^T  (bf16 in, fp32 acc) ----------
template <int EPI>
__global__ __launch_bounds__(256, 2)
void k_gemm_bt(const bf16* __restrict__ A, const bf16* __restrict__ Bt,
               const float* __restrict__ bias, const float* __restrict__ res,
               void* __restrict__ Cp, int M, int N, int K) {
  __shared__ __attribute__((aligned(16))) bf16 As[128 * 32];
  __shared__ __attribute__((aligned(16))) bf16 Bs[128 * 32];
  int m0 = blockIdx.x * 128, n0 = blockIdx.y * 128;
  int tid = threadIdx.x, lane = tid & 63, wave = tid >> 6;
  int wm = (wave >> 1) * 64, wn = (wave & 1) * 64;
  int quad = lane >> 4, l15 = lane & 15;
  f32x4 acc[4][4];
#pragma unroll
  for (int i = 0; i < 4; ++i)
#pragma unroll
    for (int j = 0; j < 4; ++j)
#pragma unroll
      for (int r = 0; r < 4; ++r) acc[i][j][r] = 0.0f;
  int srow = wave * 16 + (lane >> 2), scol = (lane & 3) * 8;
  const bf16* ga = A + (size_t)(m0 + srow) * K + scol;
  const bf16* gb = Bt + (size_t)(n0 + srow) * K + scol;
  bf16* la = As + srow * 32 + scol;
  bf16* lb = Bs + srow * 32 + scol;
  for (int k0 = 0; k0 < K; k0 += 32) {
    gl16(ga, la);
    gl16(ga + (size_t)64 * K, la + 64 * 32);
    gl16(gb, lb);
    gl16(gb + (size_t)64 * K, lb + 64 * 32);
    ga += 32; gb += 32;
    __syncthreads();
    bf16x8 af[4], bfr[4];
#pragma unroll
    for (int i = 0; i < 4; ++i) af[i] = *(const bf16x8*)(&As[(wm + i * 16 + l15) * 32 + quad * 8]);
#pragma unroll
    for (int i = 0; i < 4; ++i) bfr[i] = *(const bf16x8*)(&Bs[(wn + i * 16 + l15) * 32 + quad * 8]);
#pragma unroll
    for (int mi = 0; mi < 4; ++mi)
#pragma unroll
      for (int ni = 0; ni < 4; ++ni)
        acc[mi][ni] = MFMA(af[mi], bfr[ni], acc[mi][ni]);
    __syncthreads();
  }
#pragma unroll
  for (int mi = 0; mi < 4; ++mi) {
#pragma unroll
    for (int r = 0; r < 4; ++r) {
      int row = m0 + wm + mi * 16 + quad * 4 + r;
      if (row >= M) continue;
#pragma unroll
      for (int ni = 0; ni < 4; ++ni) {
        int col = n0 + wn + ni * 16 + l15;
        float v = acc[mi][ni][r];
        if (EPI == 0) {
          ((bf16*)Cp)[(size_t)row * N + col] = (bf16)v;
        } else {
          ((float*)Cp)[(size_t)row * N + col] =
              v + bias[col] + res[(size_t)row * N + col];
        }
      }
    }
  }
}

// ---------- GEMM + GeGLU, 128x128 tile, dual accumulators ----------
__global__ __launch_bounds__(256, 2)
void k_gemm_geglu(const bf16* __restrict__ A, const bf16* __restrict__ W1t,
                  const float* __restrict__ b1, bf16* __restrict__ Hg,
                  int M, int K) {
  __shared__ __attribute__((aligned(16))) bf16 As[128 * 32];
  __shared__ __attribute__((aligned(16))) bf16 Bu[128 * 32];
  __shared__ __attribute__((aligned(16))) bf16 Bg[128 * 32];
  const int N = 4096;
  int m0 = blockIdx.x * 128, n0 = blockIdx.y * 128;
  int tid = threadIdx.x, lane = tid & 63, wave = tid >> 6;
  int wm = (wave >> 1) * 64, wn = (wave & 1) * 64;
  int quad = lane >> 4, l15 = lane & 15;
  f32x4 accu[4][4], accg[4][4];
#pragma unroll
  for (int i = 0; i < 4; ++i)
#pragma unroll
    for (int j = 0; j < 4; ++j)
#pragma unroll
      for (int r = 0; r < 4; ++r) { accu[i][j][r] = 0.0f; accg[i][j][r] = 0.0f; }
  int srow = wave * 16 + (lane >> 2), scol = (lane & 3) * 8;
  const bf16* ga = A + (size_t)(m0 + srow) * K + scol;
  const bf16* gu = W1t + (size_t)(n0 + srow) * K + scol;
  const bf16* gg = W1t + (size_t)(n0 + srow + 4096) * K + scol;
  bf16* la = As + srow * 32 + scol;
  bf16* lu = Bu + srow * 32 + scol;
  bf16* lg = Bg + srow * 32 + scol;
  for (int k0 = 0; k0 < K; k0 += 32) {
    gl16(ga, la);
    gl16(ga + (size_t)64 * K, la + 64 * 32);
    gl16(gu, lu);
    gl16(gu + (size_t)64 * K, lu + 64 * 32);
    gl16(gg, lg);
    gl16(gg + (size_t)64 * K, lg + 64 * 32);
    ga += 32; gu += 32; gg += 32;
    __syncthreads();
    bf16x8 af[4], bu[4], bg[4];
#pragma unroll
    for (int i = 0; i < 4; ++i) af[i] = *(const bf16x8*)(&As[(wm + i * 16 + l15) * 32 + quad * 8]);
#pragma unroll
    for (int i = 0; i < 4; ++i) bu[i] = *(const bf16x8*)(&Bu[(wn + i * 16 + l15) * 32 + quad * 8]);
#pragma unroll
    for (int i = 0; i < 4; ++i) bg[i] = *(const bf16x8*)(&Bg[(wn + i * 16 + l15) * 32 + quad * 8]);
#pragma unroll
    for (int mi = 0; mi < 4; ++mi)
#pragma unroll
      for (int ni = 0; ni < 4; ++ni) {
        accu[mi][ni] = MFMA(af[mi], bu[ni], accu[mi][ni]);
        accg[mi][ni] = MFMA(af[mi], bg[ni], accg[mi][ni]);
      }
    __syncthreads();
  }
#pragma unroll
  for (int mi = 0; mi < 4; ++mi)
#pragma unroll
    for (int r = 0; r < 4; ++r) {
      int row = m0 + wm + mi * 16 + quad * 4 + r;
#pragma unroll
      for (int ni = 0; ni < 4; ++ni) {
        int col = n0 + wn + ni * 16 + l15;
        float u = accu[mi][ni][r] + b1[col];
        float g = accg[mi][ni][r] + b1[col + 4096];
        float ge = 0.5f * g * (1.0f + erff(g * 0.70710678118654752f));
        Hg[(size_t)row * N + col] = (bf16)(u * ge);
      }
    }
}

// ---------- Flash attention: 64 q-rows/block, 64-key chunks, pre-transposed V --
// Q,K: token-major (*,1024), head h at col h*64. VtG: [b][h][64][kvpad].
// K/V tiles live in XOR-swizzled LDS (byte ^= (row&7)<<4, stride 128B):
//   staged with global_load_lds (linear dest + inverse-swizzled SOURCE, rule #21),
//   double-buffered so tile t+1 loads fly under tile t compute (one barrier/iter).
// Softmax tracked in raw-score units; exp2 with 0.125*log2e folded into one FMA.
#define CSC 0.18033688011112042f  /* 0.125 * log2(e) */
__global__ __launch_bounds__(256, 4)
void k_flash(const bf16* __restrict__ Q, const bf16* __restrict__ Kb,
             const bf16* __restrict__ VtG, bf16* __restrict__ O,
             int Sq, int Sk, int kvrows, int kvpad) {
  __shared__ __attribute__((aligned(16))) bf16 Ks[2][64 * 64];
  __shared__ __attribute__((aligned(16))) bf16 Vs[2][64 * 64];  // Vs[d][key]
  __shared__ __attribute__((aligned(16))) bf16 Ps[4][16 * 64];
  int qt = blockIdx.x, h = blockIdx.y, b = blockIdx.z;
  int tid = threadIdx.x, lane = tid & 63, wave = tid >> 6;
  int quad = lane >> 4, l15 = lane & 15;
  // Q fragments resident in registers (loop-invariant)
  const bf16* qsrc = Q + (size_t)(b * Sq + qt * 64 + wave * 16 + l15) * 1024 + h * 64 + quad * 8;
  bf16x8 aq0 = *(const bf16x8*)qsrc;
  bf16x8 aq1 = *(const bf16x8*)(qsrc + 32);
  bf16x8 ones8;
#pragma unroll
  for (int i = 0; i < 8; ++i) ones8[i] = (bf16)1.0f;

  float m_r[4], l_r[4];
  f32x4 acc_o[4];
#pragma unroll
  for (int r = 0; r < 4; ++r) { m_r[r] = -1e30f; l_r[r] = 0.0f; }
#pragma unroll
  for (int ni = 0; ni < 4; ++ni)
#pragma unroll
    for (int r = 0; r < 4; ++r) acc_o[ni][r] = 0.0f;

  // staging geometry: 256 lanes x 16B x 2 rounds = 8KB tile.
  // round q: LDS linear byte = q*4096 + tid*16 -> row = q*32 + (tid>>3).
  // source col pre-swizzled so a (row&7)<<4-XOR READ sees logical columns.
  int srow = tid >> 3;                                   // 0..31 (round 0)
  int scol = ((tid & 7) * 8) ^ ((srow & 7) << 3);        // same for round 1 ((32+r)&7==r&7)
  const bf16* kg0 = Kb + (size_t)(b * kvrows + srow) * 1024 + h * 64 + scol;
  const bf16* vg0 = VtG + ((size_t)((b * 16 + h) * 64 + srow)) * kvpad + scol;

  int nt = (Sk + 63) >> 6;
  // prologue: stage tile 0
  {
    gl16(kg0, &Ks[0][tid * 8]);
    gl16(kg0 + (size_t)32 * 1024, &Ks[0][2048 + tid * 8]);
    gl16(vg0, &Vs[0][tid * 8]);
    gl16(vg0 + (size_t)32 * kvpad, &Vs[0][2048 + tid * 8]);
  }
  __syncthreads();

  int cur = 0;
  for (int t = 0; t < nt; ++t) {
    int k0 = t << 6;
    if (t + 1 < nt) {  // stage next tile into the other buffer (overlaps compute)
      const bf16* kg = kg0 + (size_t)(k0 + 64) * 1024;
      const bf16* vg = vg0 + (k0 + 64);
      gl16(kg, &Ks[cur ^ 1][tid * 8]);
      gl16(kg + (size_t)32 * 1024, &Ks[cur ^ 1][2048 + tid * 8]);
      gl16(vg, &Vs[cur ^ 1][tid * 8]);
      gl16(vg + (size_t)32 * kvpad, &Vs[cur ^ 1][2048 + tid * 8]);
    }
    const bf16* Kc = &Ks[cur][0];
    const bf16* Vc = &Vs[cur][0];

    // S = Q @ K^T -> sacc[ni][r] = S_raw[quad*4+r][ni*16+l15]
    f32x4 sacc[4];
#pragma unroll
    for (int ni = 0; ni < 4; ++ni)
#pragma unroll
      for (int r = 0; r < 4; ++r) sacc[ni][r] = 0.0f;
#pragma unroll
    for (int ni = 0; ni < 4; ++ni) {
      int krow = ni * 16 + l15;
      int sw = (krow & 7) << 3;
      bf16x8 bk0 = *(const bf16x8*)&Kc[krow * 64 + ((quad * 8) ^ sw)];
      bf16x8 bk1 = *(const bf16x8*)&Kc[krow * 64 + ((32 + quad * 8) ^ sw)];
      sacc[ni] = MFMA(aq0, bk0, sacc[ni]);
      sacc[ni] = MFMA(aq1, bk1, sacc[ni]);
    }
    if (k0 + 64 > Sk) {  // uniform tail-only masking
#pragma unroll
      for (int ni = 0; ni < 4; ++ni) {
        bool oob = (k0 + ni * 16 + l15 >= Sk);
#pragma unroll
        for (int r = 0; r < 4; ++r)
          if (oob) sacc[ni][r] = -1e30f;
      }
    }
    float alpha[4], mC[4];
#pragma unroll
    for (int r = 0; r < 4; ++r) {
      float v = fmaxf(fmaxf(sacc[0][r], sacc[1][r]), fmaxf(sacc[2][r], sacc[3][r]));
#pragma unroll
      for (int off = 1; off < 16; off <<= 1) v = fmaxf(v, __shfl_xor(v, off));
      float mn = fmaxf(m_r[r], v);
      alpha[r] = __builtin_amdgcn_exp2f((m_r[r] - mn) * CSC);
      m_r[r] = mn;
      mC[r] = mn * CSC;
    }
    // P (C layout) -> A layout round trip through wave-private swizzled LDS strip
    bf16* ps = &Ps[wave][0];
#pragma unroll
    for (int ni = 0; ni < 4; ++ni) {
      int col = ni * 16 + l15;
#pragma unroll
      for (int r = 0; r < 4; ++r) {
        int prow = quad * 4 + r;
        ps[prow * 64 + (col ^ ((prow & 7) << 3))] =
            (bf16)__builtin_amdgcn_exp2f(sacc[ni][r] * CSC - mC[r]);
      }
    }
    int swp = (l15 & 7) << 3;
    bf16x8 ap0 = *(const bf16x8*)&ps[l15 * 64 + ((quad * 8) ^ swp)];
    bf16x8 ap1 = *(const bf16x8*)&ps[l15 * 64 + ((32 + quad * 8) ^ swp)];
    // row-sum of P via MFMA with ones
    f32x4 psum;
#pragma unroll
    for (int r = 0; r < 4; ++r) psum[r] = 0.0f;
    psum = MFMA(ap0, ones8, psum);
    psum = MFMA(ap1, ones8, psum);
#pragma unroll
    for (int r = 0; r < 4; ++r) l_r[r] = l_r[r] * alpha[r] + psum[r];
#pragma unroll
    for (int ni = 0; ni < 4; ++ni) {
#pragma unroll
      for (int r = 0; r < 4; ++r) acc_o[ni][r] *= alpha[r];
      int vrow = ni * 16 + l15;
      int sw = (vrow & 7) << 3;
      bf16x8 bv0 = *(const bf16x8*)&Vc[vrow * 64 + ((quad * 8) ^ sw)];
      bf16x8 bv1 = *(const bf16x8*)&Vc[vrow * 64 + ((32 + quad * 8) ^ sw)];
      acc_o[ni] = MFMA(ap0, bv0, acc_o[ni]);
      acc_o[ni] = MFMA(ap1, bv1, acc_o[ni]);
    }
    __syncthreads();  // drains this wave's gl16 (vmcnt) + joins: next tile ready
    cur ^= 1;
  }
#pragma unroll
  for (int ni = 0; ni < 4; ++ni)
#pragma unroll
    for (int r = 0; r < 4; ++r) {
      int q = qt * 64 + wave * 16 + quad * 4 + r;
      float ov = acc_o[ni][r] / l_r[r];
      O[(size_t)(b * Sq + q) * 1024 + h * 64 + ni * 16 + l15] = (bf16)ov;
    }
}

extern "C" void kernel_launch(void* const* d_in, const int* in_sizes, int n_in,
                              void* d_out, int out_size, void* d_ws, size_t ws_size,
                              hipStream_t stream) {
  (void)in_sizes; (void)n_in; (void)out_size; (void)ws_size;
  const float* x = (const float*)d_in[0];
  const float* ctx = (const float*)d_in[1];
  const float* ln1_g = (const float*)d_in[2];
  const float* ln1_b = (const float*)d_in[3];
  const float* ln2_g = (const float*)d_in[4];
  const float* ln2_b = (const float*)d_in[5];
  const float* ln3_g = (const float*)d_in[6];
  const float* ln3_b = (const float*)d_in[7];
  const float* a1_wq = (const float*)d_in[8];
  const float* a1_wk = (const float*)d_in[9];
  const float* a1_wv = (const float*)d_in[10];
  const float* a1_wo = (const float*)d_in[11];
  const float* a1_bo = (const float*)d_in[12];
  const float* a2_wq = (const float*)d_in[13];
  const float* a2_wk = (const float*)d_in[14];
  const float* a2_wv = (const float*)d_in[15];
  const float* a2_wo = (const float*)d_in[16];
  const float* a2_bo = (const float*)d_in[17];
  const float* ff_w1 = (const float*)d_in[18];
  const float* ff_b1 = (const float*)d_in[19];
  const float* ff_w2 = (const float*)d_in[20];
  const float* ff_b2 = (const float*)d_in[21];
  float* xout = (float*)d_out;

  const int M = 4 * 2048;  // 8192 rows
  char* ws = (char*)d_ws;
  size_t off = 0;
  auto alloc = [&](size_t elems) -> bf16* {
    bf16* p = (bf16*)(ws + off);
    off += ((elems * sizeof(bf16)) + 255) & ~(size_t)255;
    return p;
  };
  bf16* wq1t = alloc((size_t)1024 * 1024);
  bf16* wk1t = alloc((size_t)1024 * 1024);
  bf16* wv1t = alloc((size_t)1024 * 1024);
  bf16* wo1t = alloc((size_t)1024 * 1024);
  bf16* wq2t = alloc((size_t)1024 * 1024);
  bf16* wk2t = alloc((size_t)1024 * 768);
  bf16* wv2t = alloc((size_t)1024 * 768);
  bf16* wo2t = alloc((size_t)1024 * 1024);
  bf16* w1t = alloc((size_t)8192 * 1024);
  bf16* w2t = alloc((size_t)1024 * 4096);
  bf16* lnb = alloc((size_t)M * 1024);
  bf16* qb = alloc((size_t)M * 1024);
  bf16* kb = alloc((size_t)M * 1024);
  bf16* vb = alloc((size_t)M * 1024);
  bf16* ab = alloc((size_t)M * 1024);
  bf16* ctxb = alloc((size_t)308 * 768);
  bf16* kcb = alloc((size_t)308 * 1024);
  bf16* vcb = alloc((size_t)308 * 1024);
  bf16* hgb = alloc((size_t)M * 4096);
  // Vt buffers alias hgb (attention phases finish before geglu writes hgb)
  bf16* vtb = hgb;                                   // 4*16*64*2048 = 8.4M elems
  bf16* vtcb = hgb + (size_t)4 * 16 * 64 * 2048;     // 4*16*64*128

  // running residual x lives in d_out (fp32)
  hipMemcpyAsync(xout, x, (size_t)M * 1024 * sizeof(float),
                 hipMemcpyDeviceToDevice, stream);

  // weights -> bf16 transposed (N x K)
  k_transpose_cvt<<<dim3(32, 32), 256, 0, stream>>>(a1_wq, wq1t, 1024, 1024);
  k_transpose_cvt<<<dim3(32, 32), 256, 0, stream>>>(a1_wk, wk1t, 1024, 1024);
  k_transpose_cvt<<<dim3(32, 32), 256, 0, stream>>>(a1_wv, wv1t, 1024, 1024);
  k_transpose_cvt<<<dim3(32, 32), 256, 0, stream>>>(a1_wo, wo1t, 1024, 1024);
  k_transpose_cvt<<<dim3(32, 32), 256, 0, stream>>>(a2_wq, wq2t, 1024, 1024);
  k_transpose_cvt<<<dim3(24, 32), 256, 0, stream>>>(a2_wk, wk2t, 768, 1024);
  k_transpose_cvt<<<dim3(24, 32), 256, 0, stream>>>(a2_wv, wv2t, 768, 1024);
  k_transpose_cvt<<<dim3(32, 32), 256, 0, stream>>>(a2_wo, wo2t, 1024, 1024);
  k_transpose_cvt<<<dim3(32, 256), 256, 0, stream>>>(ff_w1, w1t, 1024, 8192);
  k_transpose_cvt<<<dim3(128, 32), 256, 0, stream>>>(ff_w2, w2t, 4096, 1024);
  k_cvt<<<(308 * 768 + 255) / 256, 256, 0, stream>>>(ctx, ctxb, 308 * 768);

  // ---- self-attention ----
  k_layernorm<<<M, 256, 0, stream>>>(xout, ln1_g, ln1_b, lnb);
  k_gemm_bt<0><<<dim3(64, 8), 256, 0, stream>>>(lnb, wq1t, nullptr, nullptr, qb, M, 1024, 1024);
  k_gemm_bt<0><<<dim3(64, 8), 256, 0, stream>>>(lnb, wk1t, nullptr, nullptr, kb, M, 1024, 1024);
  k_gemm_bt<0><<<dim3(64, 8), 256, 0, stream>>>(lnb, wv1t, nullptr, nullptr, vb, M, 1024, 1024);
  k_transpose_v<<<dim3(32, 16, 4), 256, 0, stream>>>(vb, vtb, 2048, 2048);
  k_flash<<<dim3(32, 16, 4), 256, 0, stream>>>(qb, kb, vtb, ab, 2048, 2048, 2048, 2048);
  k_gemm_bt<1><<<dim3(64, 8), 256, 0, stream>>>(ab, wo1t, a1_bo, xout, xout, M, 1024, 1024);

  // ---- cross-attention ----
  k_layernorm<<<M, 256, 0, stream>>>(xout, ln2_g, ln2_b, lnb);
  k_gemm_bt<0><<<dim3(64, 8), 256, 0, stream>>>(lnb, wq2t, nullptr, nullptr, qb, M, 1024, 1024);
  k_gemm_bt<0><<<dim3(3, 8), 256, 0, stream>>>(ctxb, wk2t, nullptr, nullptr, kcb, 308, 1024, 768);
  k_gemm_bt<0><<<dim3(3, 8), 256, 0, stream>>>(ctxb, wv2t, nullptr, nullptr, vcb, 308, 1024, 768);
  k_transpose_v<<<dim3(2, 16, 4), 256, 0, stream>>>(vcb, vtcb, 77, 128);
  k_flash<<<dim3(32, 16, 4), 256, 0, stream>>>(qb, kcb, vtcb, ab, 2048, 77, 77, 128);
  k_gemm_bt<1><<<dim3(64, 8), 256, 0, stream>>>(ab, wo2t, a2_bo, xout, xout, M, 1024, 1024);

  // ---- GeGLU feed-forward ----
  k_layernorm<<<M, 256, 0, stream>>>(xout, ln3_g, ln3_b, lnb);
  k_gemm_geglu<<<dim3(64, 32), 256, 0, stream>>>(lnb, w1t, ff_b1, hgb, M, 1024);
  k_gemm_bt<1><<<dim3(64, 8), 256, 0, stream>>>(hgb, w2t, ff_b2, xout, xout, M, 1024, 4096);
}